// Round 2
// baseline (530.861 us; speedup 1.0000x reference)
//
#include <hip/hip_runtime.h>
#include <hip/hip_bf16.h>
#include <cmath>

typedef unsigned short u16;
typedef unsigned int   u32;

// B=4, C=1024, T=4096, H=16, D=64 fixed by the reference.
#define BB 4
#define CC 1024
#define TT 4096
#define HH 16
#define DD 64

using bf16x8 = __attribute__((ext_vector_type(8))) __bf16;
using f32x4  = __attribute__((ext_vector_type(4))) float;

__device__ __forceinline__ float bf2f(u16 u) {
    union { u32 i; float f; } v; v.i = ((u32)u) << 16; return v.f;
}
__device__ __forceinline__ u16 f2bf(float f) {
    union { float f; u32 i; } v; v.f = f;
    u32 x = v.i;
    return (u16)((x + 0x7fffu + ((x >> 16) & 1u)) >> 16);  // RNE
}

// ---------------------------------------------------------------------------
// fp32 -> bf16 convert (weights). n multiple of 1024; each thread 4 elems.
// ---------------------------------------------------------------------------
__global__ __launch_bounds__(256) void cvt_kernel(
    const float* __restrict__ src, u16* __restrict__ dst, int n)
{
    const int i = (blockIdx.x * 256 + threadIdx.x) * 4;
    if (i < n) {
        const float4 v = *reinterpret_cast<const float4*>(src + i);
        ushort4 o;
        o.x = f2bf(v.x); o.y = f2bf(v.y); o.z = f2bf(v.z); o.w = f2bf(v.w);
        *reinterpret_cast<ushort4*>(dst + i) = o;
    }
}

// ---------------------------------------------------------------------------
// x fp32 [B][C][T] -> xt bf16 [B][T][C]. 64x64 LDS tile.
// ---------------------------------------------------------------------------
__global__ __launch_bounds__(256) void transpose_kernel(
    const float* __restrict__ x, u16* __restrict__ xt)
{
    __shared__ u16 tile[64][65];
    const int b  = blockIdx.z;
    const int t0 = blockIdx.x * 64;
    const int c0 = blockIdx.y * 64;
    const float* xb  = x  + (size_t)b * CC * TT;
    u16*         xtb = xt + (size_t)b * TT * CC;
    #pragma unroll
    for (int p = 0; p < 16; ++p) {
        int idx = p * 256 + threadIdx.x;
        int r   = idx >> 6;   // c offset
        int col = idx & 63;   // t offset (coalesced fp32 read)
        tile[r][col] = f2bf(xb[(size_t)(c0 + r) * TT + t0 + col]);
    }
    __syncthreads();
    #pragma unroll
    for (int p = 0; p < 16; ++p) {
        int idx = p * 256 + threadIdx.x;
        int r   = idx >> 6;   // t offset
        int col = idx & 63;   // c offset (coalesced bf16 write)
        xtb[(size_t)(t0 + r) * CC + c0 + col] = tile[col][r];
    }
}

// ---------------------------------------------------------------------------
// GEMM: Y[m][n] = op( sum_k A[m][k] * W[n][k] + bias[n] )
//   A row-major [M][K] bf16, W row-major [N][K] bf16 (torch Linear layout).
//   Block tile 128x128, BK=32, 4 waves (2x2), each wave 4x4 MFMA 16x16x32.
//   MODE 0: plain -> bf16 Ybf (V)   MODE 1: elu(v)+1 -> bf16 Ybf (Q,K)
//   MODE 2: +bias +fp32 residual x[b][n][t], store fp32 Yf[b][n][t]
// ---------------------------------------------------------------------------
template <int MODE>
__global__ __launch_bounds__(256, 2) void gemm_kernel(
    const u16* __restrict__ A, const u16* __restrict__ W,
    const float* __restrict__ bias, u16* __restrict__ Ybf,
    float* __restrict__ Yf, const float* __restrict__ xres,
    int M, int N, int K)
{
    __shared__ u16 As[128 * 32];
    __shared__ u16 Ws[128 * 32];

    const int tid  = threadIdx.x;
    const int wave = tid >> 6;
    const int lane = tid & 63;
    const int wm = wave >> 1, wn = wave & 1;
    const int quad = lane >> 4, l16 = lane & 15;
    const int m0 = blockIdx.y * 128;
    const int n0 = blockIdx.x * 128;

    const int grow = tid >> 2;            // 0..63
    const int gcol = (tid & 3) * 8;       // 0,8,16,24

    f32x4 acc[4][4];
    #pragma unroll
    for (int i = 0; i < 4; ++i)
        #pragma unroll
        for (int j = 0; j < 4; ++j)
            acc[i][j] = (f32x4)0.0f;

    for (int k0 = 0; k0 < K; k0 += 32) {
        const uint4 a0 = *reinterpret_cast<const uint4*>(A + (size_t)(m0 + grow) * K + k0 + gcol);
        const uint4 a1 = *reinterpret_cast<const uint4*>(A + (size_t)(m0 + 64 + grow) * K + k0 + gcol);
        const uint4 w0 = *reinterpret_cast<const uint4*>(W + (size_t)(n0 + grow) * K + k0 + gcol);
        const uint4 w1 = *reinterpret_cast<const uint4*>(W + (size_t)(n0 + 64 + grow) * K + k0 + gcol);
        __syncthreads();   // previous iteration's LDS reads done
        *reinterpret_cast<uint4*>(&As[grow * 32 + gcol])        = a0;
        *reinterpret_cast<uint4*>(&As[(64 + grow) * 32 + gcol]) = a1;
        *reinterpret_cast<uint4*>(&Ws[grow * 32 + gcol])        = w0;
        *reinterpret_cast<uint4*>(&Ws[(64 + grow) * 32 + gcol]) = w1;
        __syncthreads();

        bf16x8 af[4], bfr[4];
        #pragma unroll
        for (int i = 0; i < 4; ++i) {
            af[i]  = *reinterpret_cast<const bf16x8*>(&As[(wm * 64 + i * 16 + l16) * 32 + quad * 8]);
            bfr[i] = *reinterpret_cast<const bf16x8*>(&Ws[(wn * 64 + i * 16 + l16) * 32 + quad * 8]);
        }
        #pragma unroll
        for (int i = 0; i < 4; ++i)
            #pragma unroll
            for (int j = 0; j < 4; ++j)
                acc[i][j] = __builtin_amdgcn_mfma_f32_16x16x32_bf16(af[i], bfr[j], acc[i][j], 0, 0, 0);
    }

    if (MODE == 2) {
        const int b     = m0 / TT;       // T divisible by 128 -> one b per block
        const int tbase = m0 - b * TT;
        #pragma unroll
        for (int i = 0; i < 4; ++i) {
            const int t = tbase + wm * 64 + i * 16 + quad * 4;
            #pragma unroll
            for (int j = 0; j < 4; ++j) {
                const int col = n0 + wn * 64 + j * 16 + l16;
                const float bv = bias[col];
                const size_t base = ((size_t)b * CC + col) * TT + t;
                const float4 rx = *reinterpret_cast<const float4*>(&xres[base]);
                float4 o;
                o.x = acc[i][j][0] + bv + rx.x;
                o.y = acc[i][j][1] + bv + rx.y;
                o.z = acc[i][j][2] + bv + rx.z;
                o.w = acc[i][j][3] + bv + rx.w;
                *reinterpret_cast<float4*>(&Yf[base]) = o;
            }
        }
    } else {
        #pragma unroll
        for (int i = 0; i < 4; ++i) {
            const int row = m0 + wm * 64 + i * 16 + quad * 4;
            #pragma unroll
            for (int j = 0; j < 4; ++j) {
                const int col = n0 + wn * 64 + j * 16 + l16;
                const float bv = bias[col];
                #pragma unroll
                for (int r = 0; r < 4; ++r) {
                    float v = acc[i][j][r] + bv;
                    if (MODE == 1) v = (v > 0.0f) ? (v + 1.0f) : __expf(v);
                    Ybf[(size_t)(row + r) * N + col] = f2bf(v);
                }
            }
        }
    }
}

// ---------------------------------------------------------------------------
// kv[b,h,d,e] = sum_t K[b,t,h,d]*V[b,t,h,e];  ksum[b,h,d] = sum_t K[b,t,h,d]
// fp32 accumulate, atomicAdd over T-chunks. Block: one (b,h) x 1024-t chunk.
// ---------------------------------------------------------------------------
__global__ __launch_bounds__(256) void kv_kernel(
    const u16* __restrict__ Km, const u16* __restrict__ Vm,
    float* __restrict__ kv, float* __restrict__ ksum)
{
    __shared__ float Ks[8][64];
    __shared__ float Vs[8][64];
    const int bh = blockIdx.x;            // 0..63
    const int b = bh >> 4, h = bh & 15;
    const int tc0 = blockIdx.y * 1024;
    const int tid = threadIdx.x;
    const int dg = (tid & 15) * 4;
    const int eg = (tid >> 4) * 4;
    const u16* Kbase = Km + (size_t)b * TT * CC + h * DD;
    const u16* Vbase = Vm + (size_t)b * TT * CC + h * DD;

    float acc[4][4];
    #pragma unroll
    for (int i = 0; i < 4; ++i)
        #pragma unroll
        for (int j = 0; j < 4; ++j) acc[i][j] = 0.0f;
    float sk[4] = {0.f, 0.f, 0.f, 0.f};

    for (int t0 = tc0; t0 < tc0 + 1024; t0 += 8) {
        __syncthreads();
        #pragma unroll
        for (int p = 0; p < 2; ++p) {
            int idx = p * 256 + tid;
            int tt = idx >> 6, c = idx & 63;
            Ks[tt][c] = bf2f(Kbase[(size_t)(t0 + tt) * CC + c]);
            Vs[tt][c] = bf2f(Vbase[(size_t)(t0 + tt) * CC + c]);
        }
        __syncthreads();
        #pragma unroll
        for (int tt = 0; tt < 8; ++tt) {
            float kk[4], vv[4];
            #pragma unroll
            for (int i = 0; i < 4; ++i) kk[i] = Ks[tt][dg + i];
            #pragma unroll
            for (int j = 0; j < 4; ++j) vv[j] = Vs[tt][eg + j];
            #pragma unroll
            for (int i = 0; i < 4; ++i)
                #pragma unroll
                for (int j = 0; j < 4; ++j) acc[i][j] += kk[i] * vv[j];
            if (eg == 0) {
                #pragma unroll
                for (int i = 0; i < 4; ++i) sk[i] += kk[i];
            }
        }
    }
    float* kvb = kv + (size_t)bh * DD * DD;
    #pragma unroll
    for (int i = 0; i < 4; ++i)
        #pragma unroll
        for (int j = 0; j < 4; ++j)
            atomicAdd(&kvb[(dg + i) * DD + (eg + j)], acc[i][j]);
    if (eg == 0) {
        #pragma unroll
        for (int i = 0; i < 4; ++i) atomicAdd(&ksum[bh * DD + dg + i], sk[i]);
    }
}

// ---------------------------------------------------------------------------
// num[t,e] = sum_d q[t,d]*kv[d,e]; z[t] = sum_d q[t,d]*ksum[d];
// attn[b,t,h*64+e] = num/(z+1e-6)  (bf16). One thread per t; kv in LDS.
// ---------------------------------------------------------------------------
__global__ __launch_bounds__(256) void attn_kernel(
    const u16* __restrict__ Q, const float* __restrict__ kv,
    const float* __restrict__ ksum, u16* __restrict__ attn)
{
    __shared__ float kvs[DD * DD];
    __shared__ float kss[DD];
    const int bh = blockIdx.x;
    const int b = bh >> 4, h = bh & 15;
    const int t = blockIdx.y * 256 + threadIdx.x;
    const float* kvb = kv + (size_t)bh * DD * DD;
    #pragma unroll
    for (int p = 0; p < 16; ++p) kvs[p * 256 + threadIdx.x] = kvb[p * 256 + threadIdx.x];
    if (threadIdx.x < DD) kss[threadIdx.x] = ksum[bh * DD + threadIdx.x];
    __syncthreads();

    const u16* qrow = Q + ((size_t)(b * TT + t)) * CC + h * DD;
    float num[DD];
    #pragma unroll
    for (int e = 0; e < DD; ++e) num[e] = 0.0f;
    float z = 0.0f;

    #pragma unroll 2
    for (int d = 0; d < DD; ++d) {
        const float qd = bf2f(qrow[d]);
        z += qd * kss[d];
        const float* krow = &kvs[d * DD];
        #pragma unroll
        for (int e = 0; e < DD; ++e) num[e] += qd * krow[e];
    }
    const float inv = 1.0f / (z + 1e-6f);
    u16* orow = attn + ((size_t)(b * TT + t)) * CC + h * DD;
    #pragma unroll
    for (int e = 0; e < DD; e += 2) {
        u32 pv = (u32)f2bf(num[e] * inv) | ((u32)f2bf(num[e + 1] * inv) << 16);
        *reinterpret_cast<u32*>(&orow[e]) = pv;
    }
}

// ---------------------------------------------------------------------------
extern "C" void kernel_launch(void* const* d_in, const int* in_sizes, int n_in,
                              void* d_out, int out_size, void* d_ws, size_t ws_size,
                              hipStream_t stream)
{
    const float* x  = (const float*)d_in[0];
    const float* Wq = (const float*)d_in[1];
    const float* bq = (const float*)d_in[2];
    const float* Wk = (const float*)d_in[3];
    const float* bk = (const float*)d_in[4];
    const float* Wv = (const float*)d_in[5];
    const float* bv = (const float*)d_in[6];
    const float* Wo = (const float*)d_in[7];
    const float* bo = (const float*)d_in[8];
    float* out = (float*)d_out;

    const int M = BB * TT;                                   // 16384
    const size_t BUF  = (size_t)BB * TT * CC * sizeof(u16);  // 32 MiB
    const size_t WBUF = (size_t)CC * CC * sizeof(u16);       // 2 MiB

    char* ws = (char*)d_ws;
    u16* xt  = (u16*)(ws);                 // reused as attn buffer later
    u16* Qb  = (u16*)(ws + BUF);
    u16* Kb  = (u16*)(ws + 2 * BUF);
    u16* Vb  = (u16*)(ws + 3 * BUF);
    u16* Wqb = (u16*)(ws + 4 * BUF);
    u16* Wkb = (u16*)(ws + 4 * BUF + WBUF);
    u16* Wvb = (u16*)(ws + 4 * BUF + 2 * WBUF);
    u16* Wob = (u16*)(ws + 4 * BUF + 3 * WBUF);
    float* kvbuf = (float*)(ws + 4 * BUF + 4 * WBUF);        // 1 MiB
    float* ksumb = (float*)(ws + 4 * BUF + 4 * WBUF
                            + (size_t)BB * HH * DD * DD * sizeof(float));
    u16* attn = xt;  // xt dead after QKV GEMMs

    hipMemsetAsync(kvbuf, 0,
        (size_t)(BB * HH * DD * DD + BB * HH * DD) * sizeof(float), stream);

    const int wn = CC * CC;                                  // 1M elems
    cvt_kernel<<<wn / 1024, 256, 0, stream>>>(Wq, Wqb, wn);
    cvt_kernel<<<wn / 1024, 256, 0, stream>>>(Wk, Wkb, wn);
    cvt_kernel<<<wn / 1024, 256, 0, stream>>>(Wv, Wvb, wn);
    cvt_kernel<<<wn / 1024, 256, 0, stream>>>(Wo, Wob, wn);

    transpose_kernel<<<dim3(TT / 64, CC / 64, BB), 256, 0, stream>>>(x, xt);

    gemm_kernel<1><<<dim3(CC / 128, M / 128), 256, 0, stream>>>(xt, Wqb, bq, Qb, nullptr, nullptr, M, CC, CC);
    gemm_kernel<1><<<dim3(CC / 128, M / 128), 256, 0, stream>>>(xt, Wkb, bk, Kb, nullptr, nullptr, M, CC, CC);
    gemm_kernel<0><<<dim3(CC / 128, M / 128), 256, 0, stream>>>(xt, Wvb, bv, Vb, nullptr, nullptr, M, CC, CC);

    kv_kernel<<<dim3(BB * HH, TT / 1024), 256, 0, stream>>>(Kb, Vb, kvbuf, ksumb);
    attn_kernel<<<dim3(BB * HH, TT / 256), 256, 0, stream>>>(Qb, kvbuf, ksumb, attn);

    gemm_kernel<2><<<dim3(CC / 128, M / 128), 256, 0, stream>>>(attn, Wob, bo, nullptr, out, x, M, CC, CC);
}

// Round 3
// 373.319 us; speedup vs baseline: 1.4220x; 1.4220x over previous
//
#include <hip/hip_runtime.h>
#include <hip/hip_bf16.h>
#include <cmath>

typedef unsigned short u16;
typedef unsigned int   u32;

#define BB 4
#define CC 1024
#define TT 4096
#define HH 16
#define DD 64

using bf16x8 = __attribute__((ext_vector_type(8))) __bf16;
using f32x4  = __attribute__((ext_vector_type(4))) float;

union FragU { bf16x8 v; u16 u[8]; };

__device__ __forceinline__ float bf2f(u16 u) {
    union { u32 i; float f; } v; v.i = ((u32)u) << 16; return v.f;
}
__device__ __forceinline__ u16 f2bf(float f) {
    union { float f; u32 i; } v; v.f = f;
    u32 x = v.i;
    return (u16)((x + 0x7fffu + ((x >> 16) & 1u)) >> 16);  // RNE
}

// async global->LDS, 16B per lane: LDS dest = wave-uniform base + lane*16
__device__ __forceinline__ void gl_lds16(const u16* g, u16* l) {
    __builtin_amdgcn_global_load_lds(
        (const __attribute__((address_space(1))) void*)g,
        (__attribute__((address_space(3))) void*)l, 16, 0, 0);
}

// ---------------------------------------------------------------------------
// fp32 -> bf16 convert (weights).
// ---------------------------------------------------------------------------
__global__ __launch_bounds__(256) void cvt_kernel(
    const float* __restrict__ src, u16* __restrict__ dst, int n)
{
    const int i = (blockIdx.x * 256 + threadIdx.x) * 4;
    if (i < n) {
        const float4 v = *reinterpret_cast<const float4*>(src + i);
        ushort4 o;
        o.x = f2bf(v.x); o.y = f2bf(v.y); o.z = f2bf(v.z); o.w = f2bf(v.w);
        *reinterpret_cast<ushort4*>(dst + i) = o;
    }
}

// ---------------------------------------------------------------------------
// x fp32 [B][C][T] -> xt bf16 [B][T][C]. 64x64 LDS tile.
// ---------------------------------------------------------------------------
__global__ __launch_bounds__(256) void transpose_kernel(
    const float* __restrict__ x, u16* __restrict__ xt)
{
    __shared__ u16 tile[64][65];
    const int b  = blockIdx.z;
    const int t0 = blockIdx.x * 64;
    const int c0 = blockIdx.y * 64;
    const float* xb  = x  + (size_t)b * CC * TT;
    u16*         xtb = xt + (size_t)b * TT * CC;
    #pragma unroll
    for (int p = 0; p < 16; ++p) {
        int idx = p * 256 + threadIdx.x;
        int r   = idx >> 6;
        int col = idx & 63;
        tile[r][col] = f2bf(xb[(size_t)(c0 + r) * TT + t0 + col]);
    }
    __syncthreads();
    #pragma unroll
    for (int p = 0; p < 16; ++p) {
        int idx = p * 256 + threadIdx.x;
        int r   = idx >> 6;
        int col = idx & 63;
        xtb[(size_t)(t0 + r) * CC + c0 + col] = tile[col][r];
    }
}

// ---------------------------------------------------------------------------
// GEMM: Y[m][n] = op( sum_k A[m][k]*W[n][k] + bias ), m97-style async staging.
// 128x128 tile, BK=32, 4 waves 2x2, 4x4 MFMA 16x16x32 per wave.
// MODE 3: fused QKV. N=3072; seg=n0>>10 selects {Q,K,V} output (contiguous
//         32MiB-apart buffers) and bias; elu+1 for seg<2. bf16 out.
// MODE 2: out-proj: +bias +fp32 residual x[b][n][t], fp32 out [b][n][t].
// ---------------------------------------------------------------------------
template <int MODE>
__global__ __launch_bounds__(256, 2) void gemm_kernel(
    const u16* __restrict__ A, const u16* __restrict__ W,
    const float* __restrict__ b0, const float* __restrict__ b1,
    const float* __restrict__ b2, u16* __restrict__ Ybf,
    float* __restrict__ Yf, const float* __restrict__ xres,
    int M, int N, int K)
{
    __shared__ u16 As[128 * 32];
    __shared__ u16 Ws[128 * 32];

    const int tid  = threadIdx.x;
    const int w    = tid >> 6;
    const int lane = tid & 63;
    const int wm = w >> 1, wn = w & 1;
    const int quad = lane >> 4, l16 = lane & 15;
    const int m0 = blockIdx.y * 128;
    const int n0 = blockIdx.x * 128;

    // async staging geometry: wave w covers 32 rows, lane -> (row, 8-elem col)
    const int r0 = 32 * w + (lane >> 2);
    const int cB = (lane & 3) * 8;

    f32x4 acc[4][4];
    #pragma unroll
    for (int i = 0; i < 4; ++i)
        #pragma unroll
        for (int j = 0; j < 4; ++j) acc[i][j] = (f32x4)0.0f;

    for (int k0 = 0; k0 < K; k0 += 32) {
        __syncthreads();   // prior tile's ds_reads complete
        gl_lds16(A + (size_t)(m0 + r0) * K + k0 + cB,      &As[(32 * w) * 32]);
        gl_lds16(A + (size_t)(m0 + r0 + 16) * K + k0 + cB, &As[(32 * w + 16) * 32]);
        gl_lds16(W + (size_t)(n0 + r0) * K + k0 + cB,      &Ws[(32 * w) * 32]);
        gl_lds16(W + (size_t)(n0 + r0 + 16) * K + k0 + cB, &Ws[(32 * w + 16) * 32]);
        __syncthreads();   // vmcnt(0) drained by compiler before barrier

        bf16x8 af[4], bfr[4];
        #pragma unroll
        for (int i = 0; i < 4; ++i) {
            af[i]  = *reinterpret_cast<const bf16x8*>(&As[(wm * 64 + i * 16 + l16) * 32 + quad * 8]);
            bfr[i] = *reinterpret_cast<const bf16x8*>(&Ws[(wn * 64 + i * 16 + l16) * 32 + quad * 8]);
        }
        #pragma unroll
        for (int i = 0; i < 4; ++i)
            #pragma unroll
            for (int j = 0; j < 4; ++j)
                acc[i][j] = __builtin_amdgcn_mfma_f32_16x16x32_bf16(af[i], bfr[j], acc[i][j], 0, 0, 0);
    }

    if (MODE == 2) {
        const int b     = m0 / TT;
        const int tbase = m0 - b * TT;
        #pragma unroll
        for (int i = 0; i < 4; ++i) {
            const int t = tbase + wm * 64 + i * 16 + quad * 4;
            #pragma unroll
            for (int j = 0; j < 4; ++j) {
                const int col = n0 + wn * 64 + j * 16 + l16;
                const float bv = b0[col];
                const size_t base = ((size_t)b * CC + col) * TT + t;
                const float4 rx = *reinterpret_cast<const float4*>(&xres[base]);
                float4 o;
                o.x = acc[i][j][0] + bv + rx.x;
                o.y = acc[i][j][1] + bv + rx.y;
                o.z = acc[i][j][2] + bv + rx.z;
                o.w = acc[i][j][3] + bv + rx.w;
                *reinterpret_cast<float4*>(&Yf[base]) = o;
            }
        }
    } else {  // MODE 3
        const int seg = n0 >> 10;
        const float* bp = (seg == 0) ? b0 : ((seg == 1) ? b1 : b2);
        u16* Yseg = Ybf + (size_t)seg * M * CC;
        #pragma unroll
        for (int i = 0; i < 4; ++i) {
            const int row = m0 + wm * 64 + i * 16 + quad * 4;
            #pragma unroll
            for (int j = 0; j < 4; ++j) {
                const int colL = (n0 & 1023) + wn * 64 + j * 16 + l16;
                const float bv = bp[colL];
                #pragma unroll
                for (int r = 0; r < 4; ++r) {
                    float v = acc[i][j][r] + bv;
                    if (seg < 2) v = (v > 0.0f) ? (v + 1.0f) : __expf(v);
                    Yseg[(size_t)(row + r) * CC + colL] = f2bf(v);
                }
            }
        }
    }
}

// ---------------------------------------------------------------------------
// kv[bh][d][e] = sum_t K[t][d]*V[t][e]  and  ksum[bh][d] = sum_t K[t][d],
// via MFMA. Block: one (b,h) x 512-t chunk, 4 waves; wave w owns d-tile w
// (16 d's) x all 64 e. A-frag = K^T (scalar LDS reads), ksum via ones-column.
// ---------------------------------------------------------------------------
__global__ __launch_bounds__(256) void kv_kernel(
    const u16* __restrict__ Km, const u16* __restrict__ Vm,
    float* __restrict__ kv, float* __restrict__ ksum)
{
    __shared__ u16 Ks[32 * 64];
    __shared__ u16 Vs[32 * 64];
    const int bh = blockIdx.x;
    const int b = bh >> 4, h = bh & 15;
    const int tc0 = blockIdx.y * 512;
    const int tid = threadIdx.x;
    const int w = tid >> 6, lane = tid & 63;
    const int quad = lane >> 4, l16 = lane & 15;
    const u16* Kbase = Km + (size_t)b * TT * CC + h * DD;
    const u16* Vbase = Vm + (size_t)b * TT * CC + h * DD;

    const int srow = 8 * w + (lane >> 3);
    const int scol = (lane & 7) * 8;

    f32x4 acc[4];
    #pragma unroll
    for (int j = 0; j < 4; ++j) acc[j] = (f32x4)0.0f;
    f32x4 ks = (f32x4)0.0f;

    FragU ones;
    #pragma unroll
    for (int j = 0; j < 8; ++j) ones.u[j] = (l16 == 0) ? 0x3F80u : 0u;

    for (int c = 0; c < 16; ++c) {
        const int t0 = tc0 + 32 * c;
        __syncthreads();
        gl_lds16(Kbase + (size_t)(t0 + srow) * CC + scol, &Ks[8 * w * 64]);
        gl_lds16(Vbase + (size_t)(t0 + srow) * CC + scol, &Vs[8 * w * 64]);
        __syncthreads();

        FragU af;            // A[m=d][k=t] = K[t][d], d = w*16 + l16
        #pragma unroll
        for (int j = 0; j < 8; ++j)
            af.u[j] = Ks[(quad * 8 + j) * 64 + w * 16 + l16];
        #pragma unroll
        for (int e4 = 0; e4 < 4; ++e4) {
            FragU bf;        // B[n=e][k=t] = V[t][e], e = e4*16 + l16
            #pragma unroll
            for (int j = 0; j < 8; ++j)
                bf.u[j] = Vs[(quad * 8 + j) * 64 + e4 * 16 + l16];
            acc[e4] = __builtin_amdgcn_mfma_f32_16x16x32_bf16(af.v, bf.v, acc[e4], 0, 0, 0);
        }
        ks = __builtin_amdgcn_mfma_f32_16x16x32_bf16(af.v, ones.v, ks, 0, 0, 0);
    }

    float* kvb = kv + (size_t)bh * DD * DD;
    #pragma unroll
    for (int e4 = 0; e4 < 4; ++e4)
        #pragma unroll
        for (int r = 0; r < 4; ++r)
            atomicAdd(&kvb[(w * 16 + quad * 4 + r) * DD + e4 * 16 + l16], acc[e4][r]);
    if (l16 == 0) {
        #pragma unroll
        for (int r = 0; r < 4; ++r)
            atomicAdd(&ksum[bh * DD + w * 16 + quad * 4 + r], ks[r]);
    }
}

// ---------------------------------------------------------------------------
// attn: num = Q . kv (M=256/block, N=64, K=64), z via ksum-column MFMA,
// out = num/(z+1e-6) -> bf16 attn buffer. B-frags built once per block.
// ---------------------------------------------------------------------------
__global__ __launch_bounds__(256) void attn_kernel(
    const u16* __restrict__ Q, const float* __restrict__ kv,
    const float* __restrict__ ksum, u16* __restrict__ attn)
{
    __shared__ float kvs[DD * DD];
    __shared__ float kss[DD];
    const int bh = blockIdx.x;
    const int b = bh >> 4, h = bh & 15;
    const int tb = blockIdx.y * 256;
    const int tid = threadIdx.x;
    const int w = tid >> 6, lane = tid & 63;
    const int quad = lane >> 4, l16 = lane & 15;

    const float* kvb = kv + (size_t)bh * DD * DD;
    {
        const float4* s4 = reinterpret_cast<const float4*>(kvb);
        float4* d4 = reinterpret_cast<float4*>(kvs);
        #pragma unroll
        for (int p = 0; p < 4; ++p) d4[p * 256 + tid] = s4[p * 256 + tid];
        if (tid < DD) kss[tid] = ksum[bh * DD + tid];
    }
    __syncthreads();

    // B-frags: B[n=e][k=d] = kv[d][e];  z-frag: col0 = ksum[d]
    FragU bf[4][2], zb[2];
    #pragma unroll
    for (int ck = 0; ck < 2; ++ck) {
        #pragma unroll
        for (int nt = 0; nt < 4; ++nt)
            #pragma unroll
            for (int j = 0; j < 8; ++j)
                bf[nt][ck].u[j] = f2bf(kvs[(ck * 32 + quad * 8 + j) * DD + nt * 16 + l16]);
        #pragma unroll
        for (int j = 0; j < 8; ++j)
            zb[ck].u[j] = (l16 == 0) ? f2bf(kss[ck * 32 + quad * 8 + j]) : 0u;
    }

    f32x4 acc[4][4], zacc[4];
    #pragma unroll
    for (int i = 0; i < 4; ++i) {
        zacc[i] = (f32x4)0.0f;
        #pragma unroll
        for (int j = 0; j < 4; ++j) acc[i][j] = (f32x4)0.0f;
    }

    const u16* Qbase = Q + ((size_t)b * TT) * CC + h * DD;
    #pragma unroll
    for (int i = 0; i < 4; ++i) {
        const int t = tb + w * 64 + i * 16 + l16;
        #pragma unroll
        for (int ck = 0; ck < 2; ++ck) {
            const bf16x8 af = *reinterpret_cast<const bf16x8*>(
                Qbase + (size_t)t * CC + ck * 32 + quad * 8);
            #pragma unroll
            for (int nt = 0; nt < 4; ++nt)
                acc[i][nt] = __builtin_amdgcn_mfma_f32_16x16x32_bf16(af, bf[nt][ck].v, acc[i][nt], 0, 0, 0);
            zacc[i] = __builtin_amdgcn_mfma_f32_16x16x32_bf16(af, zb[ck].v, zacc[i], 0, 0, 0);
        }
    }

    u16* obase = attn + ((size_t)b * TT) * CC + h * DD;
    #pragma unroll
    for (int i = 0; i < 4; ++i) {
        float inv[4];
        #pragma unroll
        for (int r = 0; r < 4; ++r) {
            const float zv = __shfl(zacc[i][r], lane & 48);  // z from l16==0 lane of same quad
            inv[r] = 1.0f / (zv + 1e-6f);
        }
        #pragma unroll
        for (int nt = 0; nt < 4; ++nt) {
            #pragma unroll
            for (int r = 0; r < 4; ++r) {
                const int t = tb + w * 64 + i * 16 + quad * 4 + r;
                obase[(size_t)t * CC + nt * 16 + l16] = f2bf(acc[i][nt][r] * inv[r]);
            }
        }
    }
}

// ---------------------------------------------------------------------------
extern "C" void kernel_launch(void* const* d_in, const int* in_sizes, int n_in,
                              void* d_out, int out_size, void* d_ws, size_t ws_size,
                              hipStream_t stream)
{
    const float* x  = (const float*)d_in[0];
    const float* Wq = (const float*)d_in[1];
    const float* bq = (const float*)d_in[2];
    const float* Wk = (const float*)d_in[3];
    const float* bk = (const float*)d_in[4];
    const float* Wv = (const float*)d_in[5];
    const float* bv = (const float*)d_in[6];
    const float* Wo = (const float*)d_in[7];
    const float* bo = (const float*)d_in[8];
    float* out = (float*)d_out;

    const int M = BB * TT;                                   // 16384
    const size_t BUF  = (size_t)BB * TT * CC * sizeof(u16);  // 32 MiB
    const size_t WBUF = (size_t)CC * CC * sizeof(u16);       // 2 MiB

    char* ws = (char*)d_ws;
    u16* xt   = (u16*)(ws);                // reused as attn buffer
    u16* Qb   = (u16*)(ws + BUF);          // Q,K,V contiguous (seg indexing)
    u16* Wcat = (u16*)(ws + 4 * BUF);      // [3072][1024] bf16
    u16* Wob  = (u16*)(ws + 4 * BUF + 3 * WBUF);
    float* kvbuf = (float*)(ws + 4 * BUF + 4 * WBUF);
    float* ksumb = (float*)(ws + 4 * BUF + 4 * WBUF
                            + (size_t)BB * HH * DD * DD * sizeof(float));
    u16* attn = xt;

    hipMemsetAsync(kvbuf, 0,
        (size_t)(BB * HH * DD * DD + BB * HH * DD) * sizeof(float), stream);

    const int wn = CC * CC;
    cvt_kernel<<<wn / 1024, 256, 0, stream>>>(Wq, Wcat, wn);
    cvt_kernel<<<wn / 1024, 256, 0, stream>>>(Wk, Wcat + (size_t)wn, wn);
    cvt_kernel<<<wn / 1024, 256, 0, stream>>>(Wv, Wcat + 2 * (size_t)wn, wn);
    cvt_kernel<<<wn / 1024, 256, 0, stream>>>(Wo, Wob, wn);

    transpose_kernel<<<dim3(TT / 64, CC / 64, BB), 256, 0, stream>>>(x, xt);

    // fused QKV: N = 3072
    gemm_kernel<3><<<dim3(3 * CC / 128, M / 128), 256, 0, stream>>>(
        xt, Wcat, bq, bk, bv, Qb, nullptr, nullptr, M, 3 * CC, CC);

    kv_kernel<<<dim3(BB * HH, TT / 512), 256, 0, stream>>>(
        Qb + (size_t)M * CC, Qb + 2 * (size_t)M * CC, kvbuf, ksumb);

    attn_kernel<<<dim3(BB * HH, TT / 256), 256, 0, stream>>>(Qb, kvbuf, ksumb, attn);

    gemm_kernel<2><<<dim3(CC / 128, M / 128), 256, 0, stream>>>(
        attn, Wob, bo, nullptr, nullptr, nullptr, out, x, M, CC, CC);
}

// Round 4
// 371.061 us; speedup vs baseline: 1.4307x; 1.0061x over previous
//
#include <hip/hip_runtime.h>
#include <hip/hip_bf16.h>
#include <cmath>

typedef unsigned short u16;
typedef unsigned int   u32;

#define BB 4
#define CC 1024
#define TT 4096
#define HH 16
#define DD 64

using bf16x8 = __attribute__((ext_vector_type(8))) __bf16;
using f32x4  = __attribute__((ext_vector_type(4))) float;

union FragU { bf16x8 v; u16 u[8]; };

__device__ __forceinline__ float bf2f(u16 u) {
    union { u32 i; float f; } v; v.i = ((u32)u) << 16; return v.f;
}
__device__ __forceinline__ u16 f2bf(float f) {
    union { float f; u32 i; } v; v.f = f;
    u32 x = v.i;
    return (u16)((x + 0x7fffu + ((x >> 16) & 1u)) >> 16);  // RNE
}

// async global->LDS, 16B per lane: LDS dest = wave-uniform base + lane*16
__device__ __forceinline__ void gl_lds16(const u16* g, u16* l) {
    __builtin_amdgcn_global_load_lds(
        (const __attribute__((address_space(1))) void*)g,
        (__attribute__((address_space(3))) void*)l, 16, 0, 0);
}

// ---------------------------------------------------------------------------
// fp32 -> bf16 convert (weights).
// ---------------------------------------------------------------------------
__global__ __launch_bounds__(256) void cvt_kernel(
    const float* __restrict__ src, u16* __restrict__ dst, int n)
{
    const int i = (blockIdx.x * 256 + threadIdx.x) * 4;
    if (i < n) {
        const float4 v = *reinterpret_cast<const float4*>(src + i);
        ushort4 o;
        o.x = f2bf(v.x); o.y = f2bf(v.y); o.z = f2bf(v.z); o.w = f2bf(v.w);
        *reinterpret_cast<ushort4*>(dst + i) = o;
    }
}

// ---------------------------------------------------------------------------
// x fp32 [B][C][T] -> xt bf16 [B][T][C]. 64x64 LDS tile.
// ---------------------------------------------------------------------------
__global__ __launch_bounds__(256) void transpose_kernel(
    const float* __restrict__ x, u16* __restrict__ xt)
{
    __shared__ u16 tile[64][65];
    const int b  = blockIdx.z;
    const int t0 = blockIdx.x * 64;
    const int c0 = blockIdx.y * 64;
    const float* xb  = x  + (size_t)b * CC * TT;
    u16*         xtb = xt + (size_t)b * TT * CC;
    #pragma unroll
    for (int p = 0; p < 16; ++p) {
        int idx = p * 256 + threadIdx.x;
        int r   = idx >> 6;
        int col = idx & 63;
        tile[r][col] = f2bf(xb[(size_t)(c0 + r) * TT + t0 + col]);
    }
    __syncthreads();
    #pragma unroll
    for (int p = 0; p < 16; ++p) {
        int idx = p * 256 + threadIdx.x;
        int r   = idx >> 6;
        int col = idx & 63;
        xtb[(size_t)(t0 + r) * CC + c0 + col] = tile[col][r];
    }
}

// ---------------------------------------------------------------------------
// GEMM: Y[m][n] = op( sum_k A[m][k]*W[n][k] + bias ), m97-style async staging
// with XOR-swizzled LDS: logical (row, group g) lives at physical group
// g ^ (row&3) ^ ((row>>2)&3)  -> ds_read_b128 bank conflicts 8-way -> 2-way.
// 128x128 tile, BK=32, 4 waves 2x2, 4x4 MFMA 16x16x32 per wave.
// MODE 3: fused QKV (N=3072, seg=n0>>10 -> {Q,K,V} + elu+1 for seg<2).
// MODE 2: out-proj: +bias +fp32 residual x[b][n][t], fp32 out [b][n][t].
// ---------------------------------------------------------------------------
template <int MODE>
__global__ __launch_bounds__(256, 2) void gemm_kernel(
    const u16* __restrict__ A, const u16* __restrict__ W,
    const float* __restrict__ b0, const float* __restrict__ b1,
    const float* __restrict__ b2, u16* __restrict__ Ybf,
    float* __restrict__ Yf, const float* __restrict__ xres,
    int M, int N, int K)
{
    __shared__ u16 As[128 * 32];
    __shared__ u16 Ws[128 * 32];

    const int tid  = threadIdx.x;
    const int w    = tid >> 6;
    const int lane = tid & 63;
    const int wm = w >> 1, wn = w & 1;
    const int quad = lane >> 4, l16 = lane & 15;
    const int m0 = blockIdx.y * 128;
    const int n0 = blockIdx.x * 128;

    // staging: wave w covers rows 32w..32w+31 (two halves of 16 rows).
    // physical slot of lane l = (row = 32w + (l>>2), group p = l&3);
    // fetch the logical group  g = p ^ (row&3) ^ ((row>>2)&3):
    const int r0 = 32 * w + (lane >> 2);
    const int cB = (((lane & 3) ^ ((lane >> 2) & 3) ^ ((lane >> 4) & 3)) * 8);

    // read-side physical group for logical row (..+l16), group quad:
    const int p8 = (quad ^ (l16 & 3) ^ ((l16 >> 2) & 3)) * 8;

    f32x4 acc[4][4];
    #pragma unroll
    for (int i = 0; i < 4; ++i)
        #pragma unroll
        for (int j = 0; j < 4; ++j) acc[i][j] = (f32x4)0.0f;

    for (int k0 = 0; k0 < K; k0 += 32) {
        __syncthreads();   // prior tile's ds_reads complete
        gl_lds16(A + (size_t)(m0 + r0) * K + k0 + cB,      &As[(32 * w) * 32]);
        gl_lds16(A + (size_t)(m0 + r0 + 16) * K + k0 + cB, &As[(32 * w + 16) * 32]);
        gl_lds16(W + (size_t)(n0 + r0) * K + k0 + cB,      &Ws[(32 * w) * 32]);
        gl_lds16(W + (size_t)(n0 + r0 + 16) * K + k0 + cB, &Ws[(32 * w + 16) * 32]);
        __syncthreads();

        bf16x8 af[4], bfr[4];
        #pragma unroll
        for (int i = 0; i < 4; ++i) {
            af[i]  = *reinterpret_cast<const bf16x8*>(&As[(wm * 64 + i * 16 + l16) * 32 + p8]);
            bfr[i] = *reinterpret_cast<const bf16x8*>(&Ws[(wn * 64 + i * 16 + l16) * 32 + p8]);
        }
        #pragma unroll
        for (int i = 0; i < 4; ++i)
            #pragma unroll
            for (int j = 0; j < 4; ++j)
                acc[i][j] = __builtin_amdgcn_mfma_f32_16x16x32_bf16(af[i], bfr[j], acc[i][j], 0, 0, 0);
    }

    if (MODE == 2) {
        const int b     = m0 / TT;
        const int tbase = m0 - b * TT;
        #pragma unroll
        for (int i = 0; i < 4; ++i) {
            const int t = tbase + wm * 64 + i * 16 + quad * 4;
            #pragma unroll
            for (int j = 0; j < 4; ++j) {
                const int col = n0 + wn * 64 + j * 16 + l16;
                const float bv = b0[col];
                const size_t base = ((size_t)b * CC + col) * TT + t;
                const float4 rx = *reinterpret_cast<const float4*>(&xres[base]);
                float4 o;
                o.x = acc[i][j][0] + bv + rx.x;
                o.y = acc[i][j][1] + bv + rx.y;
                o.z = acc[i][j][2] + bv + rx.z;
                o.w = acc[i][j][3] + bv + rx.w;
                *reinterpret_cast<float4*>(&Yf[base]) = o;
            }
        }
    } else {  // MODE 3
        const int seg = n0 >> 10;
        const float* bp = (seg == 0) ? b0 : ((seg == 1) ? b1 : b2);
        u16* Yseg = Ybf + (size_t)seg * M * CC;
        #pragma unroll
        for (int i = 0; i < 4; ++i) {
            const int row = m0 + wm * 64 + i * 16 + quad * 4;
            #pragma unroll
            for (int j = 0; j < 4; ++j) {
                const int colL = (n0 & 1023) + wn * 64 + j * 16 + l16;
                const float bv = bp[colL];
                #pragma unroll
                for (int r = 0; r < 4; ++r) {
                    float v = acc[i][j][r] + bv;
                    if (seg < 2) v = (v > 0.0f) ? (v + 1.0f) : __expf(v);
                    Yseg[(size_t)(row + r) * CC + colL] = f2bf(v);
                }
            }
        }
    }
}

// ---------------------------------------------------------------------------
// kv[bh][d][e] = sum_t K[t][d]*V[t][e]  and  ksum[bh][d] = sum_t K[t][d],
// via MFMA. Block: one (b,h) x 512-t chunk, 4 waves; wave w owns d-tile w.
// ---------------------------------------------------------------------------
__global__ __launch_bounds__(256) void kv_kernel(
    const u16* __restrict__ Km, const u16* __restrict__ Vm,
    float* __restrict__ kv, float* __restrict__ ksum)
{
    __shared__ u16 Ks[32 * 64];
    __shared__ u16 Vs[32 * 64];
    const int bh = blockIdx.x;
    const int b = bh >> 4, h = bh & 15;
    const int tc0 = blockIdx.y * 512;
    const int tid = threadIdx.x;
    const int w = tid >> 6, lane = tid & 63;
    const int quad = lane >> 4, l16 = lane & 15;
    const u16* Kbase = Km + (size_t)b * TT * CC + h * DD;
    const u16* Vbase = Vm + (size_t)b * TT * CC + h * DD;

    const int srow = 8 * w + (lane >> 3);
    const int scol = (lane & 7) * 8;

    f32x4 acc[4];
    #pragma unroll
    for (int j = 0; j < 4; ++j) acc[j] = (f32x4)0.0f;
    f32x4 ks = (f32x4)0.0f;

    FragU ones;
    #pragma unroll
    for (int j = 0; j < 8; ++j) ones.u[j] = (l16 == 0) ? 0x3F80u : 0u;

    for (int c = 0; c < 16; ++c) {
        const int t0 = tc0 + 32 * c;
        __syncthreads();
        gl_lds16(Kbase + (size_t)(t0 + srow) * CC + scol, &Ks[8 * w * 64]);
        gl_lds16(Vbase + (size_t)(t0 + srow) * CC + scol, &Vs[8 * w * 64]);
        __syncthreads();

        FragU af;            // A[m=d][k=t] = K[t][d], d = w*16 + l16
        #pragma unroll
        for (int j = 0; j < 8; ++j)
            af.u[j] = Ks[(quad * 8 + j) * 64 + w * 16 + l16];
        #pragma unroll
        for (int e4 = 0; e4 < 4; ++e4) {
            FragU bf;        // B[n=e][k=t] = V[t][e], e = e4*16 + l16
            #pragma unroll
            for (int j = 0; j < 8; ++j)
                bf.u[j] = Vs[(quad * 8 + j) * 64 + e4 * 16 + l16];
            acc[e4] = __builtin_amdgcn_mfma_f32_16x16x32_bf16(af.v, bf.v, acc[e4], 0, 0, 0);
        }
        ks = __builtin_amdgcn_mfma_f32_16x16x32_bf16(af.v, ones.v, ks, 0, 0, 0);
    }

    float* kvb = kv + (size_t)bh * DD * DD;
    #pragma unroll
    for (int e4 = 0; e4 < 4; ++e4)
        #pragma unroll
        for (int r = 0; r < 4; ++r)
            atomicAdd(&kvb[(w * 16 + quad * 4 + r) * DD + e4 * 16 + l16], acc[e4][r]);
    if (l16 == 0) {
        #pragma unroll
        for (int r = 0; r < 4; ++r)
            atomicAdd(&ksum[bh * DD + w * 16 + quad * 4 + r], ks[r]);
    }
}

// ---------------------------------------------------------------------------
// attn: num = Q . kv (M=256/block, N=64, K=64), z via ksum-column MFMA,
// out = num/(z+1e-6) -> bf16 attn buffer. B-frags built once per block.
// ---------------------------------------------------------------------------
__global__ __launch_bounds__(256) void attn_kernel(
    const u16* __restrict__ Q, const float* __restrict__ kv,
    const float* __restrict__ ksum, u16* __restrict__ attn)
{
    __shared__ float kvs[DD * DD];
    __shared__ float kss[DD];
    const int bh = blockIdx.x;
    const int b = bh >> 4, h = bh & 15;
    const int tb = blockIdx.y * 256;
    const int tid = threadIdx.x;
    const int w = tid >> 6, lane = tid & 63;
    const int quad = lane >> 4, l16 = lane & 15;

    const float* kvb = kv + (size_t)bh * DD * DD;
    {
        const float4* s4 = reinterpret_cast<const float4*>(kvb);
        float4* d4 = reinterpret_cast<float4*>(kvs);
        #pragma unroll
        for (int p = 0; p < 4; ++p) d4[p * 256 + tid] = s4[p * 256 + tid];
        if (tid < DD) kss[tid] = ksum[bh * DD + tid];
    }
    __syncthreads();

    // B-frags: B[n=e][k=d] = kv[d][e];  z-frag: col0 = ksum[d]
    FragU bf[4][2], zb[2];
    #pragma unroll
    for (int ck = 0; ck < 2; ++ck) {
        #pragma unroll
        for (int nt = 0; nt < 4; ++nt)
            #pragma unroll
            for (int j = 0; j < 8; ++j)
                bf[nt][ck].u[j] = f2bf(kvs[(ck * 32 + quad * 8 + j) * DD + nt * 16 + l16]);
        #pragma unroll
        for (int j = 0; j < 8; ++j)
            zb[ck].u[j] = (l16 == 0) ? f2bf(kss[ck * 32 + quad * 8 + j]) : 0u;
    }

    f32x4 acc[4][4], zacc[4];
    #pragma unroll
    for (int i = 0; i < 4; ++i) {
        zacc[i] = (f32x4)0.0f;
        #pragma unroll
        for (int j = 0; j < 4; ++j) acc[i][j] = (f32x4)0.0f;
    }

    const u16* Qbase = Q + ((size_t)b * TT) * CC + h * DD;
    #pragma unroll
    for (int i = 0; i < 4; ++i) {
        const int t = tb + w * 64 + i * 16 + l16;
        #pragma unroll
        for (int ck = 0; ck < 2; ++ck) {
            const bf16x8 af = *reinterpret_cast<const bf16x8*>(
                Qbase + (size_t)t * CC + ck * 32 + quad * 8);
            #pragma unroll
            for (int nt = 0; nt < 4; ++nt)
                acc[i][nt] = __builtin_amdgcn_mfma_f32_16x16x32_bf16(af, bf[nt][ck].v, acc[i][nt], 0, 0, 0);
            zacc[i] = __builtin_amdgcn_mfma_f32_16x16x32_bf16(af, zb[ck].v, zacc[i], 0, 0, 0);
        }
    }

    u16* obase = attn + ((size_t)b * TT) * CC + h * DD;
    #pragma unroll
    for (int i = 0; i < 4; ++i) {
        float inv[4];
        #pragma unroll
        for (int r = 0; r < 4; ++r) {
            const float zv = __shfl(zacc[i][r], lane & 48);
            inv[r] = 1.0f / (zv + 1e-6f);
        }
        #pragma unroll
        for (int nt = 0; nt < 4; ++nt) {
            #pragma unroll
            for (int r = 0; r < 4; ++r) {
                const int t = tb + w * 64 + i * 16 + quad * 4 + r;
                obase[(size_t)t * CC + nt * 16 + l16] = f2bf(acc[i][nt][r] * inv[r]);
            }
        }
    }
}

// ---------------------------------------------------------------------------
extern "C" void kernel_launch(void* const* d_in, const int* in_sizes, int n_in,
                              void* d_out, int out_size, void* d_ws, size_t ws_size,
                              hipStream_t stream)
{
    const float* x  = (const float*)d_in[0];
    const float* Wq = (const float*)d_in[1];
    const float* bq = (const float*)d_in[2];
    const float* Wk = (const float*)d_in[3];
    const float* bk = (const float*)d_in[4];
    const float* Wv = (const float*)d_in[5];
    const float* bv = (const float*)d_in[6];
    const float* Wo = (const float*)d_in[7];
    const float* bo = (const float*)d_in[8];
    float* out = (float*)d_out;

    const int M = BB * TT;                                   // 16384
    const size_t BUF  = (size_t)BB * TT * CC * sizeof(u16);  // 32 MiB
    const size_t WBUF = (size_t)CC * CC * sizeof(u16);       // 2 MiB

    char* ws = (char*)d_ws;
    u16* xt   = (u16*)(ws);                // reused as attn buffer
    u16* Qb   = (u16*)(ws + BUF);          // Q,K,V contiguous (seg indexing)
    u16* Wcat = (u16*)(ws + 4 * BUF);      // [3072][1024] bf16
    u16* Wob  = (u16*)(ws + 4 * BUF + 3 * WBUF);
    float* kvbuf = (float*)(ws + 4 * BUF + 4 * WBUF);
    float* ksumb = (float*)(ws + 4 * BUF + 4 * WBUF
                            + (size_t)BB * HH * DD * DD * sizeof(float));
    u16* attn = xt;

    hipMemsetAsync(kvbuf, 0,
        (size_t)(BB * HH * DD * DD + BB * HH * DD) * sizeof(float), stream);

    const int wn = CC * CC;
    cvt_kernel<<<wn / 1024, 256, 0, stream>>>(Wq, Wcat, wn);
    cvt_kernel<<<wn / 1024, 256, 0, stream>>>(Wk, Wcat + (size_t)wn, wn);
    cvt_kernel<<<wn / 1024, 256, 0, stream>>>(Wv, Wcat + 2 * (size_t)wn, wn);
    cvt_kernel<<<wn / 1024, 256, 0, stream>>>(Wo, Wob, wn);

    transpose_kernel<<<dim3(TT / 64, CC / 64, BB), 256, 0, stream>>>(x, xt);

    // fused QKV: N = 3072
    gemm_kernel<3><<<dim3(3 * CC / 128, M / 128), 256, 0, stream>>>(
        xt, Wcat, bq, bk, bv, Qb, nullptr, nullptr, M, 3 * CC, CC);

    kv_kernel<<<dim3(BB * HH, TT / 512), 256, 0, stream>>>(
        Qb + (size_t)M * CC, Qb + 2 * (size_t)M * CC, kvbuf, ksumb);

    attn_kernel<<<dim3(BB * HH, TT / 256), 256, 0, stream>>>(Qb, kvbuf, ksumb, attn);

    gemm_kernel<2><<<dim3(CC / 128, M / 128), 256, 0, stream>>>(
        attn, Wob, bo, nullptr, nullptr, nullptr, out, x, M, CC, CC);
}

// Round 5
// 357.968 us; speedup vs baseline: 1.4830x; 1.0366x over previous
//
#include <hip/hip_runtime.h>
#include <hip/hip_bf16.h>
#include <cmath>

typedef unsigned short u16;
typedef unsigned int   u32;

#define BB 4
#define CC 1024
#define TT 4096
#define HH 16
#define DD 64

using bf16x8 = __attribute__((ext_vector_type(8))) __bf16;
using f32x4  = __attribute__((ext_vector_type(4))) float;

union FragU { bf16x8 v; u16 u[8]; };

__device__ __forceinline__ float bf2f(u16 u) {
    union { u32 i; float f; } v; v.i = ((u32)u) << 16; return v.f;
}
__device__ __forceinline__ u16 f2bf(float f) {
    union { float f; u32 i; } v; v.f = f;
    u32 x = v.i;
    return (u16)((x + 0x7fffu + ((x >> 16) & 1u)) >> 16);  // RNE
}

// async global->LDS, 16B per lane: LDS dest = wave-uniform base + lane*16
__device__ __forceinline__ void gl_lds16(const u16* g, u16* l) {
    __builtin_amdgcn_global_load_lds(
        (const __attribute__((address_space(1))) void*)g,
        (__attribute__((address_space(3))) void*)l, 16, 0, 0);
}

// ---------------------------------------------------------------------------
// fp32 -> bf16 convert (weights).
// ---------------------------------------------------------------------------
__global__ __launch_bounds__(256) void cvt_kernel(
    const float* __restrict__ src, u16* __restrict__ dst, int n)
{
    const int i = (blockIdx.x * 256 + threadIdx.x) * 4;
    if (i < n) {
        const float4 v = *reinterpret_cast<const float4*>(src + i);
        ushort4 o;
        o.x = f2bf(v.x); o.y = f2bf(v.y); o.z = f2bf(v.z); o.w = f2bf(v.w);
        *reinterpret_cast<ushort4*>(dst + i) = o;
    }
}

// ---------------------------------------------------------------------------
// x fp32 [B][C][T] -> xt bf16 [B][T][C]. 256c x 64t tile; u32-packed writes
// give 256B-contiguous stores. Pad 258 -> <=2-way LDS conflicts.
// ---------------------------------------------------------------------------
__global__ __launch_bounds__(256) void transpose_kernel(
    const float* __restrict__ x, u16* __restrict__ xt)
{
    __shared__ u16 tile[64 * 258];   // [t][c padded]
    const int b  = blockIdx.z;
    const int t0 = blockIdx.x * 64;
    const int c0 = blockIdx.y * 256;
    const float* xb  = x  + (size_t)b * CC * TT;
    u16*         xtb = xt + (size_t)b * TT * CC;

    const int tcol = threadIdx.x & 63;
    const int rw   = threadIdx.x >> 6;     // 0..3
    #pragma unroll 8
    for (int p = 0; p < 64; ++p) {
        const int cr = p * 4 + rw;         // 0..255
        tile[tcol * 258 + cr] = f2bf(xb[(size_t)(c0 + cr) * TT + t0 + tcol]);
    }
    __syncthreads();
    const int cp = threadIdx.x & 127;      // u32 pair index (c = 2*cp)
    const int th = threadIdx.x >> 7;       // 0..1
    #pragma unroll 8
    for (int q = 0; q < 32; ++q) {
        const int tr = q * 2 + th;         // 0..63
        const u32 v = *reinterpret_cast<const u32*>(&tile[tr * 258 + cp * 2]);
        *reinterpret_cast<u32*>(&xtb[(size_t)(t0 + tr) * CC + c0 + cp * 2]) = v;
    }
}

// ---------------------------------------------------------------------------
// GEMM: Y[m][n] = op( sum_k A[m][k]*W[n][k] + bias ).  BK=64, async 16B
// staging, XOR-swizzle over 8 16B-groups per 64-elem row (bank-balanced).
// 128x128 tile, 4 waves 2x2, per-wave 4x4 MFMA 16x16x32, 2 k-subs per tile.
// MODE 3: fused QKV (N=3072, seg=n0>>10 -> {Q,K,V}, elu+1 for seg<2), bf16.
// MODE 2: out-proj +bias +fp32 residual, epilogue through LDS for
//         256B-contiguous fp32 stores along T.
// ---------------------------------------------------------------------------
template <int MODE>
__global__ __launch_bounds__(256, 2) void gemm_kernel(
    const u16* __restrict__ A, const u16* __restrict__ W,
    const float* __restrict__ b0, const float* __restrict__ b1,
    const float* __restrict__ b2, u16* __restrict__ Ybf,
    float* __restrict__ Yf, const float* __restrict__ xres,
    int M, int N, int K)
{
    __shared__ char smem[34048];           // As+Ws (32KB) / Cs (64*133*4)
    u16* As = (u16*)smem;                  // [128][64]
    u16* Ws = (u16*)(smem + 16384);        // [128][64]

    const int tid  = threadIdx.x;
    const int w    = tid >> 6;
    const int lane = tid & 63;
    const int wm = w >> 1, wn = w & 1;
    const int quad = lane >> 4, l16 = lane & 15;
    const int m0 = blockIdx.y * 128;
    const int n0 = blockIdx.x * 128;

    // staging: wave w stages rows 32w..32w+31, 4 instrs x 8 rows each.
    // lane -> (row-in-chunk = l>>3, phys group = l&7); fetch logical group
    // (l&7) ^ (row&7) so reads can un-swizzle.
    const int srow = lane >> 3;
    const int scol = ((lane & 7) ^ srow) * 8;

    f32x4 acc[4][4];
    #pragma unroll
    for (int i = 0; i < 4; ++i)
        #pragma unroll
        for (int j = 0; j < 4; ++j) acc[i][j] = (f32x4)0.0f;

    for (int k0 = 0; k0 < K; k0 += 64) {
        __syncthreads();
        #pragma unroll
        for (int s = 0; s < 4; ++s)
            gl_lds16(A + (size_t)(m0 + 32 * w + 8 * s + srow) * K + k0 + scol,
                     &As[(32 * w + 8 * s) * 64]);
        #pragma unroll
        for (int s = 0; s < 4; ++s)
            gl_lds16(W + (size_t)(n0 + 32 * w + 8 * s + srow) * K + k0 + scol,
                     &Ws[(32 * w + 8 * s) * 64]);
        __syncthreads();

        #pragma unroll
        for (int sub = 0; sub < 2; ++sub) {
            const int pg = (((sub << 2) | quad) ^ (l16 & 7)) * 8;
            bf16x8 af[4], bfr[4];
            #pragma unroll
            for (int i = 0; i < 4; ++i) {
                af[i]  = *reinterpret_cast<const bf16x8*>(&As[(wm * 64 + i * 16 + l16) * 64 + pg]);
                bfr[i] = *reinterpret_cast<const bf16x8*>(&Ws[(wn * 64 + i * 16 + l16) * 64 + pg]);
            }
            #pragma unroll
            for (int i = 0; i < 4; ++i)
                #pragma unroll
                for (int j = 0; j < 4; ++j)
                    acc[i][j] = __builtin_amdgcn_mfma_f32_16x16x32_bf16(af[i], bfr[j], acc[i][j], 0, 0, 0);
        }
    }

    if (MODE == 2) {
        float* Cs = (float*)smem;          // [64][133]
        const int b     = m0 / TT;
        const int tbase = m0 - b * TT;
        const int cl    = lane >> 4;       // col sub 0..3
        #pragma unroll
        for (int hh = 0; hh < 2; ++hh) {
            __syncthreads();
            if (wm == hh) {
                #pragma unroll
                for (int i = 0; i < 4; ++i)
                    #pragma unroll
                    for (int j = 0; j < 4; ++j)
                        #pragma unroll
                        for (int r = 0; r < 4; ++r)
                            Cs[(i * 16 + quad * 4 + r) * 133 + wn * 64 + j * 16 + l16] = acc[i][j][r];
            }
            __syncthreads();
            #pragma unroll
            for (int p = 0; p < 8; ++p) {
                const int col = p * 16 + w * 4 + cl;   // 0..127
                const int tl  = l16 * 4;               // 0..60
                float4 v;
                v.x = Cs[(tl + 0) * 133 + col];
                v.y = Cs[(tl + 1) * 133 + col];
                v.z = Cs[(tl + 2) * 133 + col];
                v.w = Cs[(tl + 3) * 133 + col];
                const float bv = b0[n0 + col];
                const size_t base = ((size_t)b * CC + n0 + col) * TT + tbase + hh * 64 + tl;
                const float4 rx = *reinterpret_cast<const float4*>(&xres[base]);
                v.x += bv + rx.x; v.y += bv + rx.y;
                v.z += bv + rx.z; v.w += bv + rx.w;
                *reinterpret_cast<float4*>(&Yf[base]) = v;
            }
        }
    } else {  // MODE 3
        const int seg = n0 >> 10;
        const float* bp = (seg == 0) ? b0 : ((seg == 1) ? b1 : b2);
        u16* Yseg = Ybf + (size_t)seg * M * CC;
        #pragma unroll
        for (int i = 0; i < 4; ++i) {
            const int row = m0 + wm * 64 + i * 16 + quad * 4;
            #pragma unroll
            for (int j = 0; j < 4; ++j) {
                const int colL = (n0 & 1023) + wn * 64 + j * 16 + l16;
                const float bv = bp[colL];
                #pragma unroll
                for (int r = 0; r < 4; ++r) {
                    float v = acc[i][j][r] + bv;
                    if (seg < 2) v = (v > 0.0f) ? (v + 1.0f) : __expf(v);
                    Yseg[(size_t)(row + r) * CC + colL] = f2bf(v);
                }
            }
        }
    }
}

// ---------------------------------------------------------------------------
// kv[bh][d][e] = sum_t K[t][d]*V[t][e]  and  ksum[bh][d] = sum_t K[t][d],
// via MFMA. Block: one (b,h) x 512-t chunk, 4 waves; wave w owns d-tile w.
// ---------------------------------------------------------------------------
__global__ __launch_bounds__(256) void kv_kernel(
    const u16* __restrict__ Km, const u16* __restrict__ Vm,
    float* __restrict__ kv, float* __restrict__ ksum)
{
    __shared__ u16 Ks[32 * 64];
    __shared__ u16 Vs[32 * 64];
    const int bh = blockIdx.x;
    const int b = bh >> 4, h = bh & 15;
    const int tc0 = blockIdx.y * 512;
    const int tid = threadIdx.x;
    const int w = tid >> 6, lane = tid & 63;
    const int quad = lane >> 4, l16 = lane & 15;
    const u16* Kbase = Km + (size_t)b * TT * CC + h * DD;
    const u16* Vbase = Vm + (size_t)b * TT * CC + h * DD;

    const int srow = 8 * w + (lane >> 3);
    const int scol = (lane & 7) * 8;

    f32x4 acc[4];
    #pragma unroll
    for (int j = 0; j < 4; ++j) acc[j] = (f32x4)0.0f;
    f32x4 ks = (f32x4)0.0f;

    FragU ones;
    #pragma unroll
    for (int j = 0; j < 8; ++j) ones.u[j] = (l16 == 0) ? 0x3F80u : 0u;

    for (int c = 0; c < 16; ++c) {
        const int t0 = tc0 + 32 * c;
        __syncthreads();
        gl_lds16(Kbase + (size_t)(t0 + srow) * CC + scol, &Ks[8 * w * 64]);
        gl_lds16(Vbase + (size_t)(t0 + srow) * CC + scol, &Vs[8 * w * 64]);
        __syncthreads();

        FragU af;            // A[m=d][k=t] = K[t][d], d = w*16 + l16
        #pragma unroll
        for (int j = 0; j < 8; ++j)
            af.u[j] = Ks[(quad * 8 + j) * 64 + w * 16 + l16];
        #pragma unroll
        for (int e4 = 0; e4 < 4; ++e4) {
            FragU bf;        // B[n=e][k=t] = V[t][e], e = e4*16 + l16
            #pragma unroll
            for (int j = 0; j < 8; ++j)
                bf.u[j] = Vs[(quad * 8 + j) * 64 + e4 * 16 + l16];
            acc[e4] = __builtin_amdgcn_mfma_f32_16x16x32_bf16(af.v, bf.v, acc[e4], 0, 0, 0);
        }
        ks = __builtin_amdgcn_mfma_f32_16x16x32_bf16(af.v, ones.v, ks, 0, 0, 0);
    }

    float* kvb = kv + (size_t)bh * DD * DD;
    #pragma unroll
    for (int e4 = 0; e4 < 4; ++e4)
        #pragma unroll
        for (int r = 0; r < 4; ++r)
            atomicAdd(&kvb[(w * 16 + quad * 4 + r) * DD + e4 * 16 + l16], acc[e4][r]);
    if (l16 == 0) {
        #pragma unroll
        for (int r = 0; r < 4; ++r)
            atomicAdd(&ksum[bh * DD + w * 16 + quad * 4 + r], ks[r]);
    }
}

// ---------------------------------------------------------------------------
// attn: num = Q . kv (M=256/block, N=64, K=64), z via ksum-column MFMA,
// out = num/(z+1e-6) -> bf16 attn buffer. B-frags built once per block.
// ---------------------------------------------------------------------------
__global__ __launch_bounds__(256) void attn_kernel(
    const u16* __restrict__ Q, const float* __restrict__ kv,
    const float* __restrict__ ksum, u16* __restrict__ attn)
{
    __shared__ float kvs[DD * DD];
    __shared__ float kss[DD];
    const int bh = blockIdx.x;
    const int b = bh >> 4, h = bh & 15;
    const int tb = blockIdx.y * 256;
    const int tid = threadIdx.x;
    const int w = tid >> 6, lane = tid & 63;
    const int quad = lane >> 4, l16 = lane & 15;

    const float* kvb = kv + (size_t)bh * DD * DD;
    {
        const float4* s4 = reinterpret_cast<const float4*>(kvb);
        float4* d4 = reinterpret_cast<float4*>(kvs);
        #pragma unroll
        for (int p = 0; p < 4; ++p) d4[p * 256 + tid] = s4[p * 256 + tid];
        if (tid < DD) kss[tid] = ksum[bh * DD + tid];
    }
    __syncthreads();

    FragU bf[4][2], zb[2];
    #pragma unroll
    for (int ck = 0; ck < 2; ++ck) {
        #pragma unroll
        for (int nt = 0; nt < 4; ++nt)
            #pragma unroll
            for (int j = 0; j < 8; ++j)
                bf[nt][ck].u[j] = f2bf(kvs[(ck * 32 + quad * 8 + j) * DD + nt * 16 + l16]);
        #pragma unroll
        for (int j = 0; j < 8; ++j)
            zb[ck].u[j] = (l16 == 0) ? f2bf(kss[ck * 32 + quad * 8 + j]) : 0u;
    }

    f32x4 acc[4][4], zacc[4];
    #pragma unroll
    for (int i = 0; i < 4; ++i) {
        zacc[i] = (f32x4)0.0f;
        #pragma unroll
        for (int j = 0; j < 4; ++j) acc[i][j] = (f32x4)0.0f;
    }

    const u16* Qbase = Q + ((size_t)b * TT) * CC + h * DD;
    #pragma unroll
    for (int i = 0; i < 4; ++i) {
        const int t = tb + w * 64 + i * 16 + l16;
        #pragma unroll
        for (int ck = 0; ck < 2; ++ck) {
            const bf16x8 af = *reinterpret_cast<const bf16x8*>(
                Qbase + (size_t)t * CC + ck * 32 + quad * 8);
            #pragma unroll
            for (int nt = 0; nt < 4; ++nt)
                acc[i][nt] = __builtin_amdgcn_mfma_f32_16x16x32_bf16(af, bf[nt][ck].v, acc[i][nt], 0, 0, 0);
            zacc[i] = __builtin_amdgcn_mfma_f32_16x16x32_bf16(af, zb[ck].v, zacc[i], 0, 0, 0);
        }
    }

    u16* obase = attn + ((size_t)b * TT) * CC + h * DD;
    #pragma unroll
    for (int i = 0; i < 4; ++i) {
        float inv[4];
        #pragma unroll
        for (int r = 0; r < 4; ++r) {
            const float zv = __shfl(zacc[i][r], lane & 48);
            inv[r] = 1.0f / (zv + 1e-6f);
        }
        #pragma unroll
        for (int nt = 0; nt < 4; ++nt) {
            #pragma unroll
            for (int r = 0; r < 4; ++r) {
                const int t = tb + w * 64 + i * 16 + quad * 4 + r;
                obase[(size_t)t * CC + nt * 16 + l16] = f2bf(acc[i][nt][r] * inv[r]);
            }
        }
    }
}

// ---------------------------------------------------------------------------
extern "C" void kernel_launch(void* const* d_in, const int* in_sizes, int n_in,
                              void* d_out, int out_size, void* d_ws, size_t ws_size,
                              hipStream_t stream)
{
    const float* x  = (const float*)d_in[0];
    const float* Wq = (const float*)d_in[1];
    const float* bq = (const float*)d_in[2];
    const float* Wk = (const float*)d_in[3];
    const float* bk = (const float*)d_in[4];
    const float* Wv = (const float*)d_in[5];
    const float* bv = (const float*)d_in[6];
    const float* Wo = (const float*)d_in[7];
    const float* bo = (const float*)d_in[8];
    float* out = (float*)d_out;

    const int M = BB * TT;                                   // 16384
    const size_t BUF  = (size_t)BB * TT * CC * sizeof(u16);  // 32 MiB
    const size_t WBUF = (size_t)CC * CC * sizeof(u16);       // 2 MiB

    char* ws = (char*)d_ws;
    u16* xt   = (u16*)(ws);                // reused as attn buffer
    u16* Qb   = (u16*)(ws + BUF);          // Q,K,V contiguous (seg indexing)
    u16* Wcat = (u16*)(ws + 4 * BUF);      // [3072][1024] bf16
    u16* Wob  = (u16*)(ws + 4 * BUF + 3 * WBUF);
    float* kvbuf = (float*)(ws + 4 * BUF + 4 * WBUF);
    float* ksumb = (float*)(ws + 4 * BUF + 4 * WBUF
                            + (size_t)BB * HH * DD * DD * sizeof(float));
    u16* attn = xt;

    hipMemsetAsync(kvbuf, 0,
        (size_t)(BB * HH * DD * DD + BB * HH * DD) * sizeof(float), stream);

    const int wn = CC * CC;
    cvt_kernel<<<wn / 1024, 256, 0, stream>>>(Wq, Wcat, wn);
    cvt_kernel<<<wn / 1024, 256, 0, stream>>>(Wk, Wcat + (size_t)wn, wn);
    cvt_kernel<<<wn / 1024, 256, 0, stream>>>(Wv, Wcat + 2 * (size_t)wn, wn);
    cvt_kernel<<<wn / 1024, 256, 0, stream>>>(Wo, Wob, wn);

    transpose_kernel<<<dim3(TT / 64, CC / 256, BB), 256, 0, stream>>>(x, xt);

    // fused QKV: N = 3072
    gemm_kernel<3><<<dim3(3 * CC / 128, M / 128), 256, 0, stream>>>(
        xt, Wcat, bq, bk, bv, Qb, nullptr, nullptr, M, 3 * CC, CC);

    kv_kernel<<<dim3(BB * HH, TT / 512), 256, 0, stream>>>(
        Qb + (size_t)M * CC, Qb + 2 * (size_t)M * CC, kvbuf, ksumb);

    attn_kernel<<<dim3(BB * HH, TT / 256), 256, 0, stream>>>(Qb, kvbuf, ksumb, attn);

    gemm_kernel<2><<<dim3(CC / 128, M / 128), 256, 0, stream>>>(
        attn, Wob, bo, nullptr, nullptr, nullptr, out, x, M, CC, CC);
}

// Round 6
// 352.372 us; speedup vs baseline: 1.5065x; 1.0159x over previous
//
#include <hip/hip_runtime.h>
#include <hip/hip_bf16.h>
#include <cmath>

typedef unsigned short u16;
typedef unsigned int   u32;

#define BB 4
#define CC 1024
#define TT 4096
#define HH 16
#define DD 64

using bf16x8 = __attribute__((ext_vector_type(8))) __bf16;
using f32x4  = __attribute__((ext_vector_type(4))) float;

union FragU { bf16x8 v; u16 u[8]; };

__device__ __forceinline__ float bf2f(u16 u) {
    union { u32 i; float f; } v; v.i = ((u32)u) << 16; return v.f;
}
__device__ __forceinline__ u16 f2bf(float f) {
    union { float f; u32 i; } v; v.f = f;
    u32 x = v.i;
    return (u16)((x + 0x7fffu + ((x >> 16) & 1u)) >> 16);  // RNE
}

// async global->LDS, 16B per lane: LDS dest = wave-uniform base + lane*16
__device__ __forceinline__ void gl_lds16(const u16* g, u16* l) {
    __builtin_amdgcn_global_load_lds(
        (const __attribute__((address_space(1))) void*)g,
        (__attribute__((address_space(3))) void*)l, 16, 0, 0);
}

// ---------------------------------------------------------------------------
// Fused prep: zone 0 (ids 0..1023)    x fp32 [B][C][T] -> xt bf16 [B][T][C]
//             zone 1 (ids 1024..5119) weight fp32->bf16 cvt (Wq,Wk,Wv,Wo)
//             zone 2 (ids 5120..5379) zero kvbuf+ksum (266240 floats)
// ---------------------------------------------------------------------------
__global__ __launch_bounds__(256) void prep_kernel(
    const float* __restrict__ x,
    const float* __restrict__ Wq, const float* __restrict__ Wk,
    const float* __restrict__ Wv, const float* __restrict__ Wo,
    u16* __restrict__ xt, u16* __restrict__ Wcat, u16* __restrict__ Wob,
    float* __restrict__ kvz)
{
    __shared__ u16 tile[64 * 258];
    const int id  = blockIdx.x;
    const int tid = threadIdx.x;

    if (id < 1024) {
        const int t0 = (id & 63) * 64;
        const int c0 = ((id >> 6) & 3) * 256;
        const int b  = id >> 8;
        const float* xb  = x  + (size_t)b * CC * TT;
        u16*         xtb = xt + (size_t)b * TT * CC;
        const int tcol = tid & 63;
        const int rw   = tid >> 6;
        #pragma unroll 8
        for (int p = 0; p < 64; ++p) {
            const int cr = p * 4 + rw;
            tile[tcol * 258 + cr] = f2bf(xb[(size_t)(c0 + cr) * TT + t0 + tcol]);
        }
        __syncthreads();
        const int cp = tid & 127;
        const int th = tid >> 7;
        #pragma unroll 8
        for (int q = 0; q < 32; ++q) {
            const int tr = q * 2 + th;
            const u32 v = *reinterpret_cast<const u32*>(&tile[tr * 258 + cp * 2]);
            *reinterpret_cast<u32*>(&xtb[(size_t)(t0 + tr) * CC + c0 + cp * 2]) = v;
        }
    } else if (id < 5120) {
        const int id2  = id - 1024;
        const int wsel = id2 >> 10;
        const int i    = ((id2 & 1023) * 256 + tid) * 4;
        const float* src = (wsel == 0) ? Wq : (wsel == 1) ? Wk : (wsel == 2) ? Wv : Wo;
        u16* dst = (wsel < 3) ? (Wcat + (size_t)wsel * CC * CC) : Wob;
        const float4 v = *reinterpret_cast<const float4*>(src + i);
        ushort4 o;
        o.x = f2bf(v.x); o.y = f2bf(v.y); o.z = f2bf(v.z); o.w = f2bf(v.w);
        *reinterpret_cast<ushort4*>(dst + i) = o;
    } else {
        const int idx = ((id - 5120) * 256 + tid) * 4;   // 260*1024 = 266240 exact
        *reinterpret_cast<float4*>(&kvz[idx]) = (float4){0.f, 0.f, 0.f, 0.f};
    }
}

// ---------------------------------------------------------------------------
// GEMM: Y[m][n] = op( sum_k A[m][k]*W[n][k] + bias ).  BK=64, async 16B
// staging, XOR swizzle over 8 groups per 64-elem row (bank-balanced).
// MODE 3: fused QKV (N=3072): seg0=Q row-major [t][c] elu+1;
//         seg1=K transposed [c][t] elu+1; seg2=V transposed [c][t] plain.
// MODE 2: out-proj +bias +fp32 residual, LDS-bounced fp32 stores along T.
// ---------------------------------------------------------------------------
template <int MODE>
__global__ __launch_bounds__(256, 2) void gemm_kernel(
    const u16* __restrict__ A, const u16* __restrict__ W,
    const float* __restrict__ b0, const float* __restrict__ b1,
    const float* __restrict__ b2, u16* __restrict__ Ybf,
    float* __restrict__ Yf, const float* __restrict__ xres,
    int M, int N, int K)
{
    __shared__ char smem[34048];           // As+Ws (32KB) / Cs (64*133*4)
    u16* As = (u16*)smem;                  // [128][64]
    u16* Ws = (u16*)(smem + 16384);        // [128][64]

    const int tid  = threadIdx.x;
    const int w    = tid >> 6;
    const int lane = tid & 63;
    const int wm = w >> 1, wn = w & 1;
    const int quad = lane >> 4, l16 = lane & 15;
    const int m0 = blockIdx.y * 128;
    const int n0 = blockIdx.x * 128;

    const int srow = lane >> 3;
    const int scol = ((lane & 7) ^ srow) * 8;

    f32x4 acc[4][4];
    #pragma unroll
    for (int i = 0; i < 4; ++i)
        #pragma unroll
        for (int j = 0; j < 4; ++j) acc[i][j] = (f32x4)0.0f;

    for (int k0 = 0; k0 < K; k0 += 64) {
        __syncthreads();
        #pragma unroll
        for (int s = 0; s < 4; ++s)
            gl_lds16(A + (size_t)(m0 + 32 * w + 8 * s + srow) * K + k0 + scol,
                     &As[(32 * w + 8 * s) * 64]);
        #pragma unroll
        for (int s = 0; s < 4; ++s)
            gl_lds16(W + (size_t)(n0 + 32 * w + 8 * s + srow) * K + k0 + scol,
                     &Ws[(32 * w + 8 * s) * 64]);
        __syncthreads();

        #pragma unroll
        for (int sub = 0; sub < 2; ++sub) {
            const int pg = (((sub << 2) | quad) ^ (l16 & 7)) * 8;
            bf16x8 af[4], bfr[4];
            #pragma unroll
            for (int i = 0; i < 4; ++i) {
                af[i]  = *reinterpret_cast<const bf16x8*>(&As[(wm * 64 + i * 16 + l16) * 64 + pg]);
                bfr[i] = *reinterpret_cast<const bf16x8*>(&Ws[(wn * 64 + i * 16 + l16) * 64 + pg]);
            }
            #pragma unroll
            for (int i = 0; i < 4; ++i)
                #pragma unroll
                for (int j = 0; j < 4; ++j)
                    acc[i][j] = __builtin_amdgcn_mfma_f32_16x16x32_bf16(af[i], bfr[j], acc[i][j], 0, 0, 0);
        }
    }

    if (MODE == 2) {
        float* Cs = (float*)smem;          // [64][133]
        const int b     = m0 / TT;
        const int tbase = m0 - b * TT;
        const int cl    = lane >> 4;
        #pragma unroll
        for (int hh = 0; hh < 2; ++hh) {
            __syncthreads();
            if (wm == hh) {
                #pragma unroll
                for (int i = 0; i < 4; ++i)
                    #pragma unroll
                    for (int j = 0; j < 4; ++j)
                        #pragma unroll
                        for (int r = 0; r < 4; ++r)
                            Cs[(i * 16 + quad * 4 + r) * 133 + wn * 64 + j * 16 + l16] = acc[i][j][r];
            }
            __syncthreads();
            #pragma unroll
            for (int p = 0; p < 8; ++p) {
                const int col = p * 16 + w * 4 + cl;
                const int tl  = l16 * 4;
                float4 v;
                v.x = Cs[(tl + 0) * 133 + col];
                v.y = Cs[(tl + 1) * 133 + col];
                v.z = Cs[(tl + 2) * 133 + col];
                v.w = Cs[(tl + 3) * 133 + col];
                const float bv = b0[n0 + col];
                const size_t base = ((size_t)b * CC + n0 + col) * TT + tbase + hh * 64 + tl;
                const float4 rx = *reinterpret_cast<const float4*>(&xres[base]);
                v.x += bv + rx.x; v.y += bv + rx.y;
                v.z += bv + rx.z; v.w += bv + rx.w;
                *reinterpret_cast<float4*>(&Yf[base]) = v;
            }
        }
    } else {  // MODE 3
        const int seg = n0 >> 10;
        const float* bp = (seg == 0) ? b0 : ((seg == 1) ? b1 : b2);
        if (seg == 0) {
            // Q: row-major [b*T + t][c], elu+1
            #pragma unroll
            for (int i = 0; i < 4; ++i) {
                const int row = m0 + wm * 64 + i * 16 + quad * 4;
                #pragma unroll
                for (int j = 0; j < 4; ++j) {
                    const int colL = wn * 64 + j * 16 + l16;
                    const float bv = bp[colL];
                    #pragma unroll
                    for (int r = 0; r < 4; ++r) {
                        float v = acc[i][j][r] + bv;
                        v = (v > 0.0f) ? (v + 1.0f) : __expf(v);
                        Ybf[(size_t)(row + r) * CC + colL] = f2bf(v);
                    }
                }
            }
        } else {
            // K/V: transposed [b][c][t] (t-contiguous), K gets elu+1
            u16* Yt = Ybf + (size_t)seg * M * CC;
            const int b = m0 / TT;
            #pragma unroll
            for (int i = 0; i < 4; ++i) {
                const int t = (m0 - b * TT) + wm * 64 + i * 16 + quad * 4;
                #pragma unroll
                for (int j = 0; j < 4; ++j) {
                    const int colL = (n0 & 1023) + wn * 64 + j * 16 + l16;
                    const float bv = bp[colL];
                    ushort4 o;
                    #pragma unroll
                    for (int r = 0; r < 4; ++r) {
                        float v = acc[i][j][r] + bv;
                        if (seg == 1) v = (v > 0.0f) ? (v + 1.0f) : __expf(v);
                        ((u16*)&o)[r] = f2bf(v);
                    }
                    *reinterpret_cast<ushort4*>(
                        &Yt[((size_t)(b * CC + colL)) * TT + t]) = o;
                }
            }
        }
    }
}

// ---------------------------------------------------------------------------
// kv[bh][d][e] = sum_t K[t][d]*V[t][e]; ksum[bh][d] = sum_t K[t][d].
// Kt/Vt are [b][c][t] -> all fragments are swizzled ds_read_b128.
// Block: one (b,h) x 512-t chunk; wave w owns d-tile w. 64 t per iter.
// ---------------------------------------------------------------------------
__global__ __launch_bounds__(256) void kv_kernel(
    const u16* __restrict__ Kt, const u16* __restrict__ Vt,
    float* __restrict__ kv, float* __restrict__ ksum)
{
    __shared__ u16 Ks[64 * 64];
    __shared__ u16 Vs[64 * 64];
    const int bh = blockIdx.x;
    const int b = bh >> 4, h = bh & 15;
    const int tc0 = blockIdx.y * 512;
    const int tid = threadIdx.x;
    const int w = tid >> 6, lane = tid & 63;
    const int quad = lane >> 4, l16 = lane & 15;

    const u16* Kg = Kt + ((size_t)(b * CC + h * DD)) * TT;
    const u16* Vg = Vt + ((size_t)(b * CC + h * DD)) * TT;

    const int srow = lane >> 3;                       // 0..7
    const int scol = ((lane & 7) ^ srow) * 8;         // XOR-swizzled group

    f32x4 acc[4];
    #pragma unroll
    for (int j = 0; j < 4; ++j) acc[j] = (f32x4)0.0f;
    f32x4 ks = (f32x4)0.0f;

    FragU ones;
    #pragma unroll
    for (int j = 0; j < 8; ++j) ones.u[j] = (l16 == 0) ? 0x3F80u : 0u;

    for (int it = 0; it < 8; ++it) {
        const int t0 = tc0 + it * 64;
        __syncthreads();
        #pragma unroll
        for (int s = 0; s < 2; ++s) {
            gl_lds16(Kg + (size_t)(16 * w + 8 * s + srow) * TT + t0 + scol,
                     &Ks[(16 * w + 8 * s) * 64]);
            gl_lds16(Vg + (size_t)(16 * w + 8 * s + srow) * TT + t0 + scol,
                     &Vs[(16 * w + 8 * s) * 64]);
        }
        __syncthreads();

        #pragma unroll
        for (int sub = 0; sub < 2; ++sub) {
            const int pg = (((sub << 2) | quad) ^ (l16 & 7)) * 8;
            const bf16x8 af = *reinterpret_cast<const bf16x8*>(
                &Ks[(w * 16 + l16) * 64 + pg]);       // A[d][t]
            #pragma unroll
            for (int e4 = 0; e4 < 4; ++e4) {
                const bf16x8 bfv = *reinterpret_cast<const bf16x8*>(
                    &Vs[(e4 * 16 + l16) * 64 + pg]);  // B[e][t]
                acc[e4] = __builtin_amdgcn_mfma_f32_16x16x32_bf16(af, bfv, acc[e4], 0, 0, 0);
            }
            ks = __builtin_amdgcn_mfma_f32_16x16x32_bf16(af, ones.v, ks, 0, 0, 0);
        }
    }

    float* kvb = kv + (size_t)bh * DD * DD;
    #pragma unroll
    for (int e4 = 0; e4 < 4; ++e4)
        #pragma unroll
        for (int r = 0; r < 4; ++r)
            atomicAdd(&kvb[(w * 16 + quad * 4 + r) * DD + e4 * 16 + l16], acc[e4][r]);
    if (l16 == 0) {
        #pragma unroll
        for (int r = 0; r < 4; ++r)
            atomicAdd(&ksum[bh * DD + w * 16 + quad * 4 + r], ks[r]);
    }
}

// ---------------------------------------------------------------------------
// attn: num = Q . kv, z via ksum-column MFMA, out = num/(z+1e-6) -> bf16.
// Q staged through LDS (async DMA, swizzled b128 reads).
// ---------------------------------------------------------------------------
__global__ __launch_bounds__(256) void attn_kernel(
    const u16* __restrict__ Q, const float* __restrict__ kv,
    const float* __restrict__ ksum, u16* __restrict__ attn)
{
    __shared__ u16 Qs[256 * 64];     // 32 KB
    __shared__ float kvs[DD * DD];   // 16 KB
    __shared__ float kss[DD];
    const int bh = blockIdx.x;
    const int b = bh >> 4, h = bh & 15;
    const int tb = blockIdx.y * 256;
    const int tid = threadIdx.x;
    const int w = tid >> 6, lane = tid & 63;
    const int quad = lane >> 4, l16 = lane & 15;

    // stage Q tile [256 t][64 c] via DMA, XOR-swizzled groups
    {
        const int srow = lane >> 3;
        const int scol = ((lane & 7) ^ srow) * 8;
        const u16* Qg = Q + ((size_t)(b * TT + tb)) * CC + h * DD;
        #pragma unroll
        for (int p = 0; p < 8; ++p)
            gl_lds16(Qg + (size_t)(64 * w + 8 * p + srow) * CC + scol,
                     &Qs[(64 * w + 8 * p) * 64]);
    }
    {
        const float4* s4 = reinterpret_cast<const float4*>(kv + (size_t)bh * DD * DD);
        float4* d4 = reinterpret_cast<float4*>(kvs);
        #pragma unroll
        for (int p = 0; p < 4; ++p) d4[p * 256 + tid] = s4[p * 256 + tid];
        if (tid < DD) kss[tid] = ksum[bh * DD + tid];
    }
    __syncthreads();

    FragU bf[4][2], zb[2];
    #pragma unroll
    for (int ck = 0; ck < 2; ++ck) {
        #pragma unroll
        for (int nt = 0; nt < 4; ++nt)
            #pragma unroll
            for (int j = 0; j < 8; ++j)
                bf[nt][ck].u[j] = f2bf(kvs[(ck * 32 + quad * 8 + j) * DD + nt * 16 + l16]);
        #pragma unroll
        for (int j = 0; j < 8; ++j)
            zb[ck].u[j] = (l16 == 0) ? f2bf(kss[ck * 32 + quad * 8 + j]) : 0u;
    }

    f32x4 acc[4][4], zacc[4];
    #pragma unroll
    for (int i = 0; i < 4; ++i) {
        zacc[i] = (f32x4)0.0f;
        #pragma unroll
        for (int j = 0; j < 4; ++j) acc[i][j] = (f32x4)0.0f;
    }

    #pragma unroll
    for (int i = 0; i < 4; ++i) {
        const int trow = w * 64 + i * 16 + l16;
        #pragma unroll
        for (int ck = 0; ck < 2; ++ck) {
            const int pg = (((ck << 2) | quad) ^ (l16 & 7)) * 8;
            const bf16x8 af = *reinterpret_cast<const bf16x8*>(&Qs[trow * 64 + pg]);
            #pragma unroll
            for (int nt = 0; nt < 4; ++nt)
                acc[i][nt] = __builtin_amdgcn_mfma_f32_16x16x32_bf16(af, bf[nt][ck].v, acc[i][nt], 0, 0, 0);
            zacc[i] = __builtin_amdgcn_mfma_f32_16x16x32_bf16(af, zb[ck].v, zacc[i], 0, 0, 0);
        }
    }

    u16* obase = attn + ((size_t)b * TT) * CC + h * DD;
    #pragma unroll
    for (int i = 0; i < 4; ++i) {
        float inv[4];
        #pragma unroll
        for (int r = 0; r < 4; ++r) {
            const float zv = __shfl(zacc[i][r], lane & 48);
            inv[r] = 1.0f / (zv + 1e-6f);
        }
        #pragma unroll
        for (int nt = 0; nt < 4; ++nt) {
            #pragma unroll
            for (int r = 0; r < 4; ++r) {
                const int t = tb + w * 64 + i * 16 + quad * 4 + r;
                obase[(size_t)t * CC + nt * 16 + l16] = f2bf(acc[i][nt][r] * inv[r]);
            }
        }
    }
}

// ---------------------------------------------------------------------------
extern "C" void kernel_launch(void* const* d_in, const int* in_sizes, int n_in,
                              void* d_out, int out_size, void* d_ws, size_t ws_size,
                              hipStream_t stream)
{
    const float* x  = (const float*)d_in[0];
    const float* Wq = (const float*)d_in[1];
    const float* bq = (const float*)d_in[2];
    const float* Wk = (const float*)d_in[3];
    const float* bk = (const float*)d_in[4];
    const float* Wv = (const float*)d_in[5];
    const float* bv = (const float*)d_in[6];
    const float* Wo = (const float*)d_in[7];
    const float* bo = (const float*)d_in[8];
    float* out = (float*)d_out;

    const int M = BB * TT;                                   // 16384
    const size_t BUF  = (size_t)BB * TT * CC * sizeof(u16);  // 32 MiB
    const size_t WBUF = (size_t)CC * CC * sizeof(u16);       // 2 MiB

    char* ws = (char*)d_ws;
    u16* xt   = (u16*)(ws);                // reused as attn buffer
    u16* Qb   = (u16*)(ws + BUF);          // Q [t][c]; Kt,Vt [c][t] at +1,+2 BUF
    u16* Wcat = (u16*)(ws + 4 * BUF);      // [3072][1024] bf16
    u16* Wob  = (u16*)(ws + 4 * BUF + 3 * WBUF);
    float* kvbuf = (float*)(ws + 4 * BUF + 4 * WBUF);        // 1 MiB + 16 KiB (incl ksum)
    float* ksumb = kvbuf + (size_t)BB * HH * DD * DD;
    u16* attn = xt;

    // prep: transpose (1024) + weight cvt (4096) + kv zero (260)
    prep_kernel<<<5380, 256, 0, stream>>>(x, Wq, Wk, Wv, Wo, xt, Wcat, Wob, kvbuf);

    // fused QKV: N = 3072 (Q row-major; K,V transposed [c][t])
    gemm_kernel<3><<<dim3(3 * CC / 128, M / 128), 256, 0, stream>>>(
        xt, Wcat, bq, bk, bv, Qb, nullptr, nullptr, M, 3 * CC, CC);

    kv_kernel<<<dim3(BB * HH, TT / 512), 256, 0, stream>>>(
        Qb + (size_t)M * CC, Qb + 2 * (size_t)M * CC, kvbuf, ksumb);

    attn_kernel<<<dim3(BB * HH, TT / 256), 256, 0, stream>>>(Qb, kvbuf, ksumb, attn);

    gemm_kernel<2><<<dim3(CC / 128, M / 128), 256, 0, stream>>>(
        attn, Wob, bo, nullptr, nullptr, nullptr, out, x, M, CC, CC);
}